// Round 14
// baseline (495.810 us; speedup 1.0000x reference)
//
#include <hip/hip_runtime.h>
#include <hip/hip_bf16.h>

// Problem constants
#define BDIM 2
#define LDIM 512
#define CDIM 576
#define HDIM 8
#define CPD  128
#define DK3  24
#define INV_DIV 0.117851130197757920f   // 1/sqrt(72)

// Workspace layout (floats).
static constexpr size_t OFF_Q    = 0;                       // [B,3,H,L,24] 589824
static constexpr size_t OFF_K    = 589824;
static constexpr size_t OFF_V    = 1179648;
static constexpr size_t OFF_G    = 1769472;
static constexpr size_t OFF_BIAS = 2359296;                 // [B,H,L,L] 4194304 ; bias, then convsum
static constexpr size_t OFF_ORI  = OFF_BIAS + 4194304;      // [B,3,H,L,L] 12582912
static constexpr size_t OFF_QK   = OFF_ORI + 12582912;      // xn alias region
static constexpr size_t OFF_H    = OFF_QK + 12582912;       // [B*L,576]   589824
static constexpr size_t OFF_WPH  = OFF_H + 589824;          // [8][128] = 1024
static constexpr size_t OFF_CS   = OFF_WPH + 1024;          // [16]
static constexpr size_t OFF_XN   = OFF_QK;                  // alias: xn dead before k_conv

__device__ __forceinline__ float gelu_exact(float v) {
    return 0.5f * v * (1.f + erff(v * 0.70710678118654752f));
}

// XCD-aware bijective block swizzle (8 XCDs; requires nwg % 8 == 0).
// HW round-robins blockIdx across XCDs; this maps each XCD to a contiguous
// chunk of logical tiles so data-sharing neighbors hit the same L2.
__device__ __forceinline__ int xcd_swz(int bid, int nwg) {
    return (bid & 7) * (nwg >> 3) + (bid >> 3);
}

typedef float __attribute__((ext_vector_type(4))) f32x4;
__device__ __forceinline__ void nt_store4(float* p, float a, float b, float c, float d) {
    f32x4 t = {a, b, c, d};
    __builtin_nontemporal_store(t, (f32x4*)p);
}

// ---------------------------------------------------------------------------
// K0: prep for pairbias (parallelized: 256 threads, shfl reduce).
// ---------------------------------------------------------------------------
__global__ __launch_bounds__(256) void k_prep(
    const float* __restrict__ ln2w, const float* __restrict__ ln2b,
    const float* __restrict__ Wp, const float* __restrict__ bp,
    float* __restrict__ wph, float* __restrict__ csum)
{
    __shared__ float wl[1024];
    const int tid = threadIdx.x;
    for (int i = tid; i < 1024; i += 256) {
        int h = i >> 7, d = i & 127;
        float v = ln2w[d] * Wp[d * 8 + h];
        wl[i] = v; wph[i] = v;
    }
    __syncthreads();
    const int h = tid >> 5, c4 = tid & 31;
    float p = wl[h * 128 + c4 * 4] + wl[h * 128 + c4 * 4 + 1]
            + wl[h * 128 + c4 * 4 + 2] + wl[h * 128 + c4 * 4 + 3];
#pragma unroll
    for (int o = 1; o < 32; o <<= 1) p += __shfl_xor(p, o);
    if (c4 == 0) csum[h] = p;
    float q = 0.f;
#pragma unroll
    for (int k = 0; k < 4; ++k) { int d = c4 * 4 + k; q = fmaf(ln2b[d], Wp[d * 8 + h], q); }
#pragma unroll
    for (int o = 1; o < 32; o <<= 1) q += __shfl_xor(q, o);
    if (c4 == 0) csum[8 + h] = q + bp[h];
}

// ---------------------------------------------------------------------------
// K1a: LN(x) -> xn[1024][576] global.  grid=256, wave per row.
// ---------------------------------------------------------------------------
__global__ __launch_bounds__(256) void k_ln(
    const float* __restrict__ x, const float* __restrict__ ln1w, const float* __restrict__ ln1b,
    float* __restrict__ xn)
{
    const int tid = threadIdx.x;
    const int wid = tid >> 6, lane = tid & 63;
    const int row = blockIdx.x * 4 + wid;
    const float* xr = x + (size_t)row * CDIM;
    float vals[9]; float s = 0.f, sq = 0.f;
#pragma unroll
    for (int u = 0; u < 9; ++u) {
        float v = xr[lane + 64 * u];
        vals[u] = v; s += v; sq += v * v;
    }
#pragma unroll
    for (int o = 32; o; o >>= 1) { s += __shfl_xor(s, o); sq += __shfl_xor(sq, o); }
    float m = s * (1.f / 576.f);
    float inv = rsqrtf(sq * (1.f / 576.f) - m * m + 1e-6f);
    float* xo = xn + (size_t)row * CDIM;
#pragma unroll
    for (int u = 0; u < 9; ++u) {
        int idx = lane + 64 * u;
        xo[idx] = (vals[u] - m) * inv * ln1w[idx] + ln1b[idx];
    }
}

// ---------------------------------------------------------------------------
// K1b: projection GEMM.  grid = 4*3*16 = 192.
// ---------------------------------------------------------------------------
__global__ __launch_bounds__(256) void k_proj(
    const float* __restrict__ xn,
    const float* __restrict__ Wq, const float* __restrict__ bq,
    const float* __restrict__ Wk, const float* __restrict__ bk,
    const float* __restrict__ Wv, const float* __restrict__ bv,
    const float* __restrict__ Wg, const float* __restrict__ bg,
    float* __restrict__ qo, float* __restrict__ ko, float* __restrict__ vo, float* __restrict__ go)
{
    __shared__ float As[192 * 64];   // [k][row]
    __shared__ float Bs[32 * 192];   // [k2][col]
    const int tid = threadIdx.x;
    const int bx = blockIdx.x;
    const int mi = bx / 48, rem = bx % 48;
    const int g = rem >> 4, rb = rem & 15;
    const int row0 = rb * 64;

    const float* W  = mi == 0 ? Wq : mi == 1 ? Wk : mi == 2 ? Wv : Wg;
    const float* bb = mi == 0 ? bq : mi == 1 ? bk : mi == 2 ? bv : bg;
    float* op       = mi == 0 ? qo : mi == 1 ? ko : mi == 2 ? vo : go;

    {   // stage As transposed: As[k][r] = xn[row0+r][g*192+k]
        const int r = tid & 63, k4b = tid >> 6;
#pragma unroll
        for (int it = 0; it < 12; ++it) {
            int k4 = k4b + it * 4;
            float4 v = *(const float4*)&xn[(size_t)(row0 + r) * 576 + g * 192 + k4 * 4];
            As[(k4 * 4 + 0) * 64 + r] = v.x;
            As[(k4 * 4 + 1) * 64 + r] = v.y;
            As[(k4 * 4 + 2) * 64 + r] = v.z;
            As[(k4 * 4 + 3) * 64 + r] = v.w;
        }
    }

    const int rg = tid >> 4, cg = tid & 15;
    const int r0 = rg * 4, c0 = cg * 12;
    float acc[4][12] = {};

    for (int kk = 0; kk < 192; kk += 32) {
        __syncthreads();
#pragma unroll
        for (int i = 0; i < 6; ++i) {
            int f = tid + 256 * i;          // 0..1535
            int k2 = f / 48, c4 = f % 48;
            *(float4*)&Bs[k2 * 192 + c4 * 4] = *(const float4*)&W[(size_t)(kk + k2) * 192 + c4 * 4];
        }
        __syncthreads();
#pragma unroll
        for (int k2 = 0; k2 < 32; ++k2) {
            const float4 a  = *(const float4*)&As[(kk + k2) * 64 + r0];
            const float4 b0 = *(const float4*)&Bs[k2 * 192 + c0];
            const float4 b1 = *(const float4*)&Bs[k2 * 192 + c0 + 4];
            const float4 b2 = *(const float4*)&Bs[k2 * 192 + c0 + 8];
            const float ar[4] = {a.x, a.y, a.z, a.w};
#pragma unroll
            for (int r = 0; r < 4; ++r) {
                acc[r][0] = fmaf(ar[r], b0.x, acc[r][0]);
                acc[r][1] = fmaf(ar[r], b0.y, acc[r][1]);
                acc[r][2] = fmaf(ar[r], b0.z, acc[r][2]);
                acc[r][3] = fmaf(ar[r], b0.w, acc[r][3]);
                acc[r][4] = fmaf(ar[r], b1.x, acc[r][4]);
                acc[r][5] = fmaf(ar[r], b1.y, acc[r][5]);
                acc[r][6] = fmaf(ar[r], b1.z, acc[r][6]);
                acc[r][7] = fmaf(ar[r], b1.w, acc[r][7]);
                acc[r][8] = fmaf(ar[r], b2.x, acc[r][8]);
                acc[r][9] = fmaf(ar[r], b2.y, acc[r][9]);
                acc[r][10] = fmaf(ar[r], b2.z, acc[r][10]);
                acc[r][11] = fmaf(ar[r], b2.w, acc[r][11]);
            }
        }
    }

    const int h = cg >> 1, d24 = (cg & 1) * 12;
    const float4 bj0 = *(const float4*)&bb[c0];
    const float4 bj1 = *(const float4*)&bb[c0 + 4];
    const float4 bj2 = *(const float4*)&bb[c0 + 8];
#pragma unroll
    for (int r = 0; r < 4; ++r) {
        int row = row0 + r0 + r;
        int b = row >> 9, l = row & 511;
        float* o = op + ((((size_t)b * 3 + g) * HDIM + h) * LDIM + l) * DK3 + d24;
        *(float4*)(o + 0) = make_float4(acc[r][0] + bj0.x, acc[r][1] + bj0.y,
                                        acc[r][2] + bj0.z, acc[r][3] + bj0.w);
        *(float4*)(o + 4) = make_float4(acc[r][4] + bj1.x, acc[r][5] + bj1.y,
                                        acc[r][6] + bj1.z, acc[r][7] + bj1.w);
        *(float4*)(o + 8) = make_float4(acc[r][8] + bj2.x, acc[r][9] + bj2.y,
                                        acc[r][10] + bj2.z, acc[r][11] + bj2.w);
    }
}

// ---------------------------------------------------------------------------
// K2: pairBias.  ONE THREAD = ONE (b,i,j) ROW.  LN folded analytically.
// grid=2048 (XCD-swizzled).
// ---------------------------------------------------------------------------
__global__ __launch_bounds__(256) void k_pairbias(
    const float* __restrict__ pairX, const float* __restrict__ wph,
    const float* __restrict__ csum, float* __restrict__ bias)
{
    const int sb = xcd_swz(blockIdx.x, 2048);
    const int row = sb * 256 + threadIdx.x;
    const float* rp = pairX + (size_t)row * CPD;

    float acc[8] = {};
    float sum = 0.f, sumsq = 0.f;
    for (int s = 0; s < 8; ++s) {
        float rr[16];
        *(float4*)&rr[0]  = *(const float4*)(rp + s * 16 + 0);
        *(float4*)&rr[4]  = *(const float4*)(rp + s * 16 + 4);
        *(float4*)&rr[8]  = *(const float4*)(rp + s * 16 + 8);
        *(float4*)&rr[12] = *(const float4*)(rp + s * 16 + 12);
#pragma unroll
        for (int k = 0; k < 16; ++k) { sum += rr[k]; sumsq = fmaf(rr[k], rr[k], sumsq); }
        const float* wp_s = wph + s * 16;
#pragma unroll
        for (int h = 0; h < 8; ++h) {
            const float* w = wp_s + h * 128;   // uniform address -> s_load
#pragma unroll
            for (int k = 0; k < 16; ++k) acc[h] = fmaf(rr[k], w[k], acc[h]);
        }
    }
    const float m = sum * (1.f / 128.f);
    const float inv = rsqrtf(sumsq * (1.f / 128.f) - m * m + 1e-6f);
    const int b = row >> 18;
    const int ij = row & 262143;
    float* bo = bias + ((size_t)b << 21) + ij;
#pragma unroll
    for (int h = 0; h < 8; ++h) {
        float o = inv * (acc[h] - m * csum[h]) + csum[8 + h];
        bo[(size_t)h << 18] = o;
    }
}

// ---------------------------------------------------------------------------
// K3: oriQK = q.k^T (K=24) + bias.  grid=768 (XCD-swizzled: 16 itiles of a
// bch land on one XCD -> K panel L2-resident across them).
// ---------------------------------------------------------------------------
__global__ __launch_bounds__(256) void k_qkmat(
    const float* __restrict__ q, const float* __restrict__ k,
    const float* __restrict__ bias, float* __restrict__ oriQK)
{
    __shared__ float Kl[512 * 28];   // 57.3 KB
    __shared__ float Ql[32 * 28];
    const int tid = threadIdx.x;
    const int bx = xcd_swz(blockIdx.x, 768);
    const int bch = bx >> 4;       // b*24 + c*8 + h
    const int itile = bx & 15;
    const float* kp = k + (size_t)bch * 512 * 24;
    const float* qp = q + (size_t)bch * 512 * 24 + (size_t)itile * 32 * 24;
    for (int idx = tid; idx < 512 * 24; idx += 256) {
        int j = idx / 24, d = idx - j * 24;
        Kl[j * 28 + d] = kp[idx];
    }
    for (int idx = tid; idx < 32 * 24; idx += 256) {
        int i = idx / 24, d = idx - i * 24;
        Ql[i * 28 + d] = qp[idx];
    }
    __syncthreads();

    const int ti = tid >> 4, tj = tid & 15;
    const int b = bch / 24, h = bch & 7;
    const float* biasp = bias + ((size_t)(b * 8 + h) * 512 + itile * 32) * 512;
    float* outp = oriQK + (size_t)bch * 262144 + (size_t)itile * 32 * 512;

    for (int cc = 0; cc < 4; ++cc) {
        float acc[2][8] = {};
#pragma unroll
        for (int d4 = 0; d4 < 6; ++d4) {
            const float4 q0 = *(const float4*)&Ql[(ti * 2 + 0) * 28 + d4 * 4];
            const float4 q1 = *(const float4*)&Ql[(ti * 2 + 1) * 28 + d4 * 4];
#pragma unroll
            for (int u = 0; u < 8; ++u) {
                const float4 kv = *(const float4*)&Kl[(cc * 128 + u * 16 + tj) * 28 + d4 * 4];
                acc[0][u] = fmaf(q0.x, kv.x, fmaf(q0.y, kv.y, fmaf(q0.z, kv.z, fmaf(q0.w, kv.w, acc[0][u]))));
                acc[1][u] = fmaf(q1.x, kv.x, fmaf(q1.y, kv.y, fmaf(q1.z, kv.z, fmaf(q1.w, kv.w, acc[1][u]))));
            }
        }
#pragma unroll
        for (int r = 0; r < 2; ++r) {
            int i = ti * 2 + r;
#pragma unroll
            for (int u = 0; u < 8; ++u) {
                int j = cc * 128 + u * 16 + tj;
                outp[(size_t)i * 512 + j] = acc[r][u] + biasp[(size_t)i * 512 + j];
            }
        }
    }
}

// ---------------------------------------------------------------------------
// K4 v10+swz: 5x5 conv + fused out2.  No qk materialization; writes biased
// convsum [B,H,L,L]; centers accumulated in registers (static mm[8][2]).
// 32x16 tiles, grid=1024 (XCD-swizzled: neighbor tiles share halos in-L2),
// LDS 34 KB, 4 blocks/CU.
// ---------------------------------------------------------------------------
__global__ __launch_bounds__(256, 4) void k_conv(
    const float* __restrict__ oriQK, const float* __restrict__ convW, const float* __restrict__ convB,
    const float* __restrict__ Wpr, const float* __restrict__ bpr,
    float* __restrict__ convsum, float* __restrict__ out2)
{
    __shared__ float tile[8 * 36 * 24];   // 27648 B: conv tile, later gql overlay
    __shared__ float wT[1600];            // 6400 B
    const int tid = threadIdx.x;
    const int bx = xcd_swz(blockIdx.x, 1024);
    const int b = bx >> 9, rem = bx & 511;
    const int i0 = (rem >> 5) * 32, j0 = (rem & 31) * 16;

    const int jg = tid & 7, ii = tid >> 3;
    const int j2 = jg * 2;
    float acc[8][2] = {};                    // conv partial sums
    float mm[8][2] = {};                     // center sums over branches

    for (int c = 0; c < 3; ++c) {
        __syncthreads();
        for (int i = tid; i < 1600; i += 256) {
            int h = i & 7, rest = i >> 3;
            int tap = rest % 25, hi = rest / 25;
            wT[hi * 200 + tap * 8 + h] = convW[c * 1600 + h * 200 + hi * 25 + tap];
        }
        for (int idx = tid; idx < 8 * 720; idx += 256) {
            int ch = idx / 720;
            int r = idx - ch * 720;
            int iw = r / 20, jw = r - iw * 20;
            int gi = i0 - 2 + iw, gj = j0 - 2 + jw;
            float v = 0.f;
            if ((unsigned)gi < 512u && (unsigned)gj < 512u)
                v = oriQK[((size_t)(b * 24 + c * 8 + ch) << 18) + ((size_t)gi << 9) + gj];
            tile[ch * 864 + iw * 24 + jw] = v;
        }
        __syncthreads();

        for (int hi = 0; hi < 8; ++hi) {
            const float* tch = &tile[hi * 864];
            const float* wch = &wT[hi * 200];
#pragma unroll
            for (int kh = 0; kh < 5; ++kh) {
                const float* trow = &tch[(ii + kh) * 24 + j2];
                float v[6];
                *(float2*)&v[0] = *(const float2*)&trow[0];
                *(float2*)&v[2] = *(const float2*)&trow[2];
                *(float2*)&v[4] = *(const float2*)&trow[4];
#pragma unroll
                for (int kw = 0; kw < 5; ++kw) {
                    const float4 wA = *(const float4*)&wch[(kh * 5 + kw) * 8];     // broadcast
                    const float4 wB = *(const float4*)&wch[(kh * 5 + kw) * 8 + 4]; // broadcast
#pragma unroll
                    for (int j = 0; j < 2; ++j) {
                        float vv = v[kw + j];
                        acc[0][j] = fmaf(wA.x, vv, acc[0][j]);
                        acc[1][j] = fmaf(wA.y, vv, acc[1][j]);
                        acc[2][j] = fmaf(wA.z, vv, acc[2][j]);
                        acc[3][j] = fmaf(wA.w, vv, acc[3][j]);
                        acc[4][j] = fmaf(wB.x, vv, acc[4][j]);
                        acc[5][j] = fmaf(wB.y, vv, acc[5][j]);
                        acc[6][j] = fmaf(wB.z, vv, acc[6][j]);
                        acc[7][j] = fmaf(wB.w, vv, acc[7][j]);
                    }
                }
            }
        }
        // accumulate this branch's center values (tile live, static indices)
#pragma unroll
        for (int h = 0; h < 8; ++h) {
            const float* tr = &tile[h * 864 + (ii + 2) * 24 + j2 + 2];
            mm[h][0] += tr[0];
            mm[h][1] += tr[1];
        }
    }

    // epilogue 1: write biased convsum; compute gelu(mean) from registers
    const int gi = i0 + ii, gj = j0 + j2;
    float* csb = convsum + ((size_t)(b * 8) << 18) + ((size_t)gi << 9) + gj;
#pragma unroll
    for (int h = 0; h < 8; ++h) {
        float cv = convB[h] + convB[8 + h] + convB[16 + h];   // uniform
        float cj0 = acc[h][0] + cv, cj1 = acc[h][1] + cv;
        *(float2*)(csb + ((size_t)h << 18)) = make_float2(cj0, cj1);
        acc[h][0] = gelu_exact((mm[h][0] * (1.f / 3.f) + cj0) * INV_DIV);
        acc[h][1] = gelu_exact((mm[h][1] * (1.f / 3.f) + cj1) * INV_DIV);
    }
    __syncthreads();   // all tile reads done; smem becomes gql

    // gql overlay [h][512]
    float* gql = tile;
#pragma unroll
    for (int h = 0; h < 8; ++h)
        *(float2*)&gql[h * 512 + ii * 16 + j2] = make_float2(acc[h][0], acc[h][1]);
    __syncthreads();

    // epilogue 2: out2[pos][0..127] = gq[pos] . Wpr + bpr (nontemporal)
    const int pq = tid & 31, pg = tid >> 5;
    float4 wv[8];
#pragma unroll
    for (int h = 0; h < 8; ++h) wv[h] = *(const float4*)&Wpr[h * 128 + pq * 4];
    const float4 bv = *(const float4*)&bpr[pq * 4];

    for (int it = 0; it < 64; ++it) {
        int pos = it * 8 + pg;
        float g8[8];
#pragma unroll
        for (int h = 0; h < 8; ++h) g8[h] = gql[h * 512 + pos];   // broadcast
        float ox = bv.x + g8[0]*wv[0].x + g8[1]*wv[1].x + g8[2]*wv[2].x + g8[3]*wv[3].x
                 + g8[4]*wv[4].x + g8[5]*wv[5].x + g8[6]*wv[6].x + g8[7]*wv[7].x;
        float oy = bv.y + g8[0]*wv[0].y + g8[1]*wv[1].y + g8[2]*wv[2].y + g8[3]*wv[3].y
                 + g8[4]*wv[4].y + g8[5]*wv[5].y + g8[6]*wv[6].y + g8[7]*wv[7].y;
        float oz = bv.z + g8[0]*wv[0].z + g8[1]*wv[1].z + g8[2]*wv[2].z + g8[3]*wv[3].z
                 + g8[4]*wv[4].z + g8[5]*wv[5].z + g8[6]*wv[6].z + g8[7]*wv[7].z;
        float ow = bv.w + g8[0]*wv[0].w + g8[1]*wv[1].w + g8[2]*wv[2].w + g8[3]*wv[3].w
                 + g8[4]*wv[4].w + g8[5]*wv[5].w + g8[6]*wv[6].w + g8[7]*wv[7].w;
        int oi = i0 + (pos >> 4), oj = j0 + (pos & 15);
        nt_store4(&out2[(((size_t)(b * 512 + oi) << 9) + oj) * 128 + pq * 4], ox, oy, oz, ow);
    }
}

// ---------------------------------------------------------------------------
// K6 v3: softmax + P@V + sigmoid(gate).  qk reconstructed on the fly.
// Vl stride 24 (49.2 KB -> exactly 3 blocks/CU resident; grid=768 fits in
// one residency round, no tail).  XCD-swizzled (16 itiles of a bch share V).
// ---------------------------------------------------------------------------
__global__ __launch_bounds__(256, 3) void k_softmax_pv(
    const float* __restrict__ ori, const float* __restrict__ convsum,
    const float* __restrict__ v, const float* __restrict__ gate,
    float* __restrict__ houts)
{
    __shared__ float Vl[512 * 24];   // 49.2 KB, straight copy of V panel
    const int tid = threadIdx.x;
    const int bx = xcd_swz(blockIdx.x, 768);
    const int bch = bx >> 4, itile = bx & 15;
    const float* vp = v + (size_t)bch * (512 * 24);
    for (int idx = tid; idx < 3072; idx += 256)
        *(float4*)&Vl[idx * 4] = *(const float4*)&vp[idx * 4];
    __syncthreads();

    const int wid = tid >> 6, lane = tid & 63;
    const int b = bch / 24, c = (bch % 24) >> 3, h = bch & 7;
    const int tg = lane >> 3;          // d-trio group 0..7
    for (int rr = 0; rr < 8; ++rr) {
        const int i = itile * 32 + wid * 8 + rr;
        const float* row = ori + ((size_t)bch * 512 + i) * 512;
        const float* csr = convsum + ((size_t)(b * 8 + h) * 512 + i) * 512;
        float e[8]; float mx = -1e30f;
#pragma unroll
        for (int u = 0; u < 8; ++u) {
            e[u] = (row[lane + 64 * u] + csr[lane + 64 * u]) * INV_DIV;
            mx = fmaxf(mx, e[u]);
        }
#pragma unroll
        for (int o = 32; o; o >>= 1) mx = fmaxf(mx, __shfl_xor(mx, o));
        float s = 0.f;
#pragma unroll
        for (int u = 0; u < 8; ++u) { e[u] = __expf(e[u] - mx); s += e[u]; }
#pragma unroll
        for (int o = 32; o; o >>= 1) s += __shfl_xor(s, o);
        float inv = 1.f / s;

        float4 a4[6] = {};
#pragma unroll
        for (int u = 0; u < 8; ++u) {
            float p = e[u] * inv;
            const float* vr = &Vl[(u * 64 + lane) * 24];
#pragma unroll
            for (int k = 0; k < 6; ++k) {
                float4 vv = *(const float4*)(vr + 4 * k);
                a4[k].x = fmaf(p, vv.x, a4[k].x);
                a4[k].y = fmaf(p, vv.y, a4[k].y);
                a4[k].z = fmaf(p, vv.z, a4[k].z);
                a4[k].w = fmaf(p, vv.w, a4[k].w);
            }
        }
        // stage 1: reduce over lane bits 3,4,5
#pragma unroll
        for (int k = 0; k < 6; ++k) {
            a4[k].x += __shfl_xor(a4[k].x, 8);  a4[k].y += __shfl_xor(a4[k].y, 8);
            a4[k].z += __shfl_xor(a4[k].z, 8);  a4[k].w += __shfl_xor(a4[k].w, 8);
            a4[k].x += __shfl_xor(a4[k].x, 16); a4[k].y += __shfl_xor(a4[k].y, 16);
            a4[k].z += __shfl_xor(a4[k].z, 16); a4[k].w += __shfl_xor(a4[k].w, 16);
            a4[k].x += __shfl_xor(a4[k].x, 32); a4[k].y += __shfl_xor(a4[k].y, 32);
            a4[k].z += __shfl_xor(a4[k].z, 32); a4[k].w += __shfl_xor(a4[k].w, 32);
        }
        // stage 2: lane selects d-trio tg, reduce across classes (bits 0..2)
        const float af[24] = {
            a4[0].x, a4[0].y, a4[0].z, a4[0].w, a4[1].x, a4[1].y, a4[1].z, a4[1].w,
            a4[2].x, a4[2].y, a4[2].z, a4[2].w, a4[3].x, a4[3].y, a4[3].z, a4[3].w,
            a4[4].x, a4[4].y, a4[4].z, a4[4].w, a4[5].x, a4[5].y, a4[5].z, a4[5].w };
        float w0 = tg==0?af[0]:tg==1?af[3]:tg==2?af[6]:tg==3?af[9]:tg==4?af[12]:tg==5?af[15]:tg==6?af[18]:af[21];
        float w1 = tg==0?af[1]:tg==1?af[4]:tg==2?af[7]:tg==3?af[10]:tg==4?af[13]:tg==5?af[16]:tg==6?af[19]:af[22];
        float w2 = tg==0?af[2]:tg==1?af[5]:tg==2?af[8]:tg==3?af[11]:tg==4?af[14]:tg==5?af[17]:tg==6?af[20]:af[23];
#pragma unroll
        for (int o = 1; o < 8; o <<= 1) {
            w0 += __shfl_xor(w0, o);
            w1 += __shfl_xor(w1, o);
            w2 += __shfl_xor(w2, o);
        }
        if ((lane & 7) == 0) {
            const int d0 = tg * 3;
            const float* gp = gate + ((size_t)bch * 512 + i) * 24 + d0;
            float* op = houts + ((size_t)(b * 512 + i)) * 576 + c * 192 + h * 24 + d0;
            op[0] = w0 / (1.f + __expf(-gp[0]));
            op[1] = w1 / (1.f + __expf(-gp[1]));
            op[2] = w2 / (1.f + __expf(-gp[2]));
        }
    }
}

// ---------------------------------------------------------------------------
// K7: out1 = houts @ Wo + bo + x*g.  Tiled GEMM: 32x64 tile, BK=32, grid=288.
// ---------------------------------------------------------------------------
__global__ __launch_bounds__(256) void k_out1(
    const float* __restrict__ houts, const float* __restrict__ Wo, const float* __restrict__ bo,
    const float* __restrict__ x, const float* __restrict__ gsc,
    float* __restrict__ out1)
{
    __shared__ float As[32 * 33];
    __shared__ float Bs[32 * 64];
    const int tid = threadIdx.x;
    const int mt = blockIdx.x / 9, nt = blockIdx.x % 9;
    const int m0 = mt * 32, n0 = nt * 64;
    const int tn = tid & 15, tm = tid >> 4;
    float acc[2][4] = {};

    for (int kk = 0; kk < 576; kk += 32) {
        {
            int idx = tid;
#pragma unroll
            for (int i = 0; i < 4; ++i, idx += 256) {
                int k2 = idx & 31, m = idx >> 5;
                As[m * 33 + k2] = houts[(size_t)(m0 + m) * 576 + kk + k2];
            }
        }
        {
            int idx = tid;
#pragma unroll
            for (int i = 0; i < 8; ++i, idx += 256) {
                int n = idx & 63, k2 = idx >> 6;
                Bs[k2 * 64 + n] = Wo[(size_t)(kk + k2) * 576 + n0 + n];
            }
        }
        __syncthreads();
#pragma unroll
        for (int k2 = 0; k2 < 32; ++k2) {
            float a0 = As[(tm * 2 + 0) * 33 + k2];
            float a1 = As[(tm * 2 + 1) * 33 + k2];
            const float4 bv = *(const float4*)&Bs[k2 * 64 + tn * 4];
            acc[0][0] += a0 * bv.x; acc[0][1] += a0 * bv.y; acc[0][2] += a0 * bv.z; acc[0][3] += a0 * bv.w;
            acc[1][0] += a1 * bv.x; acc[1][1] += a1 * bv.y; acc[1][2] += a1 * bv.z; acc[1][3] += a1 * bv.w;
        }
        __syncthreads();
    }

    const float gv = gsc[0];
    const float4 b4 = *(const float4*)&bo[n0 + tn * 4];
#pragma unroll
    for (int r = 0; r < 2; ++r) {
        size_t row = (size_t)m0 + tm * 2 + r;
        size_t off = row * 576 + n0 + tn * 4;
        const float4 x4 = *(const float4*)&x[off];
        nt_store4(&out1[off],
                  acc[r][0] + b4.x + x4.x * gv,
                  acc[r][1] + b4.y + x4.y * gv,
                  acc[r][2] + b4.z + x4.z * gv,
                  acc[r][3] + b4.w + x4.w * gv);
    }
}

// ---------------------------------------------------------------------------
extern "C" void kernel_launch(void* const* d_in, const int* in_sizes, int n_in,
                              void* d_out, int out_size, void* d_ws, size_t ws_size,
                              hipStream_t stream) {
    const float* x     = (const float*)d_in[0];
    const float* pairX = (const float*)d_in[1];
    const float* g     = (const float*)d_in[2];
    const float* ln1w  = (const float*)d_in[3];
    const float* ln1b  = (const float*)d_in[4];
    const float* ln2w  = (const float*)d_in[5];
    const float* ln2b  = (const float*)d_in[6];
    const float* Wq    = (const float*)d_in[7];
    const float* bq    = (const float*)d_in[8];
    const float* Wk    = (const float*)d_in[9];
    const float* bk    = (const float*)d_in[10];
    const float* Wv    = (const float*)d_in[11];
    const float* bv    = (const float*)d_in[12];
    const float* Wg    = (const float*)d_in[13];
    const float* bg    = (const float*)d_in[14];
    const float* convW = (const float*)d_in[15];
    const float* convB = (const float*)d_in[16];
    const float* Wp    = (const float*)d_in[17];
    const float* bp    = (const float*)d_in[18];
    const float* Wpr   = (const float*)d_in[19];
    const float* bpr   = (const float*)d_in[20];
    const float* Wo    = (const float*)d_in[21];
    const float* bo    = (const float*)d_in[22];

    float* ws   = (float*)d_ws;
    float* q    = ws + OFF_Q;
    float* k    = ws + OFF_K;
    float* vv   = ws + OFF_V;
    float* gt   = ws + OFF_G;
    float* bias = ws + OFF_BIAS;
    float* csb  = ws + OFF_BIAS;   // alias: convsum after bias consumed by k_qkmat
    float* ori  = ws + OFF_ORI;
    float* xn   = ws + OFF_XN;     // alias onto dead qk region
    float* hout = ws + OFF_H;
    float* wph  = ws + OFF_WPH;
    float* csum = ws + OFF_CS;

    float* out1 = (float*)d_out;
    float* out2 = out1 + 589824;

    k_prep<<<dim3(1), dim3(256), 0, stream>>>(ln2w, ln2b, Wp, bp, wph, csum);
    k_ln<<<dim3(256), dim3(256), 0, stream>>>(x, ln1w, ln1b, xn);
    k_proj<<<dim3(192), dim3(256), 0, stream>>>(xn, Wq, bq, Wk, bk, Wv, bv, Wg, bg,
                                                q, k, vv, gt);
    k_pairbias<<<dim3(2048), dim3(256), 0, stream>>>(pairX, wph, csum, bias);
    k_qkmat<<<dim3(768), dim3(256), 0, stream>>>(q, k, bias, ori);
    k_conv<<<dim3(1024), dim3(256), 0, stream>>>(ori, convW, convB, Wpr, bpr, csb, out2);
    k_softmax_pv<<<dim3(768), dim3(256), 0, stream>>>(ori, csb, vv, gt, hout);
    k_out1<<<dim3(288), dim3(256), 0, stream>>>(hout, Wo, bo, x, g, out1);
}

// Round 15
// 408.751 us; speedup vs baseline: 1.2130x; 1.2130x over previous
//
#include <hip/hip_runtime.h>
#include <hip/hip_bf16.h>

// Problem constants
#define BDIM 2
#define LDIM 512
#define CDIM 576
#define HDIM 8
#define CPD  128
#define DK3  24
#define INV_DIV 0.117851130197757920f   // 1/sqrt(72)

// Workspace layout (floats).
static constexpr size_t OFF_Q    = 0;                       // [B,3,H,L,24] 589824
static constexpr size_t OFF_K    = 589824;
static constexpr size_t OFF_V    = 1179648;
static constexpr size_t OFF_G    = 1769472;
static constexpr size_t OFF_BIAS = 2359296;                 // [B,H,L,L] 4194304
static constexpr size_t OFF_ORI  = OFF_BIAS + 4194304;      // [B,3,H,L,L] 12582912
static constexpr size_t OFF_QK   = OFF_ORI + 12582912;      // [B,3,H,L,L] qk; first 589824 aliased as xn before k_conv
static constexpr size_t OFF_H    = OFF_QK + 12582912;       // [B*L,576]   589824
static constexpr size_t OFF_WPH  = OFF_H + 589824;          // [8][128] = 1024
static constexpr size_t OFF_CS   = OFF_WPH + 1024;          // [16]
static constexpr size_t OFF_XN   = OFF_QK;                  // alias: xn dead before k_conv writes qk

__device__ __forceinline__ float gelu_exact(float v) {
    return 0.5f * v * (1.f + erff(v * 0.70710678118654752f));
}

typedef float __attribute__((ext_vector_type(4))) f32x4;
__device__ __forceinline__ void nt_store4(float* p, float a, float b, float c, float d) {
    f32x4 t = {a, b, c, d};
    __builtin_nontemporal_store(t, (f32x4*)p);
}

// ---------------------------------------------------------------------------
// K0: prep for pairbias (parallelized: 256 threads, shfl reduce).
// ---------------------------------------------------------------------------
__global__ __launch_bounds__(256) void k_prep(
    const float* __restrict__ ln2w, const float* __restrict__ ln2b,
    const float* __restrict__ Wp, const float* __restrict__ bp,
    float* __restrict__ wph, float* __restrict__ csum)
{
    __shared__ float wl[1024];
    const int tid = threadIdx.x;
    for (int i = tid; i < 1024; i += 256) {
        int h = i >> 7, d = i & 127;
        float v = ln2w[d] * Wp[d * 8 + h];
        wl[i] = v; wph[i] = v;
    }
    __syncthreads();
    const int h = tid >> 5, c4 = tid & 31;
    float p = wl[h * 128 + c4 * 4] + wl[h * 128 + c4 * 4 + 1]
            + wl[h * 128 + c4 * 4 + 2] + wl[h * 128 + c4 * 4 + 3];
#pragma unroll
    for (int o = 1; o < 32; o <<= 1) p += __shfl_xor(p, o);
    if (c4 == 0) csum[h] = p;
    float q = 0.f;
#pragma unroll
    for (int k = 0; k < 4; ++k) { int d = c4 * 4 + k; q = fmaf(ln2b[d], Wp[d * 8 + h], q); }
#pragma unroll
    for (int o = 1; o < 32; o <<= 1) q += __shfl_xor(q, o);
    if (c4 == 0) csum[8 + h] = q + bp[h];
}

// ---------------------------------------------------------------------------
// K1a: LN(x) -> xn[1024][576] global.  grid=256, wave per row.
// ---------------------------------------------------------------------------
__global__ __launch_bounds__(256) void k_ln(
    const float* __restrict__ x, const float* __restrict__ ln1w, const float* __restrict__ ln1b,
    float* __restrict__ xn)
{
    const int tid = threadIdx.x;
    const int wid = tid >> 6, lane = tid & 63;
    const int row = blockIdx.x * 4 + wid;
    const float* xr = x + (size_t)row * CDIM;
    float vals[9]; float s = 0.f, sq = 0.f;
#pragma unroll
    for (int u = 0; u < 9; ++u) {
        float v = xr[lane + 64 * u];
        vals[u] = v; s += v; sq += v * v;
    }
#pragma unroll
    for (int o = 32; o; o >>= 1) { s += __shfl_xor(s, o); sq += __shfl_xor(sq, o); }
    float m = s * (1.f / 576.f);
    float inv = rsqrtf(sq * (1.f / 576.f) - m * m + 1e-6f);
    float* xo = xn + (size_t)row * CDIM;
#pragma unroll
    for (int u = 0; u < 9; ++u) {
        int idx = lane + 64 * u;
        xo[idx] = (vals[u] - m) * inv * ln1w[idx] + ln1b[idx];
    }
}

// ---------------------------------------------------------------------------
// K1b: projection GEMM.  grid = 4*3*16 = 192.
// ---------------------------------------------------------------------------
__global__ __launch_bounds__(256) void k_proj(
    const float* __restrict__ xn,
    const float* __restrict__ Wq, const float* __restrict__ bq,
    const float* __restrict__ Wk, const float* __restrict__ bk,
    const float* __restrict__ Wv, const float* __restrict__ bv,
    const float* __restrict__ Wg, const float* __restrict__ bg,
    float* __restrict__ qo, float* __restrict__ ko, float* __restrict__ vo, float* __restrict__ go)
{
    __shared__ float As[192 * 64];   // [k][row]
    __shared__ float Bs[32 * 192];   // [k2][col]
    const int tid = threadIdx.x;
    const int bx = blockIdx.x;
    const int mi = bx / 48, rem = bx % 48;
    const int g = rem >> 4, rb = rem & 15;
    const int row0 = rb * 64;

    const float* W  = mi == 0 ? Wq : mi == 1 ? Wk : mi == 2 ? Wv : Wg;
    const float* bb = mi == 0 ? bq : mi == 1 ? bk : mi == 2 ? bv : bg;
    float* op       = mi == 0 ? qo : mi == 1 ? ko : mi == 2 ? vo : go;

    {   // stage As transposed: As[k][r] = xn[row0+r][g*192+k]
        const int r = tid & 63, k4b = tid >> 6;
#pragma unroll
        for (int it = 0; it < 12; ++it) {
            int k4 = k4b + it * 4;
            float4 v = *(const float4*)&xn[(size_t)(row0 + r) * 576 + g * 192 + k4 * 4];
            As[(k4 * 4 + 0) * 64 + r] = v.x;
            As[(k4 * 4 + 1) * 64 + r] = v.y;
            As[(k4 * 4 + 2) * 64 + r] = v.z;
            As[(k4 * 4 + 3) * 64 + r] = v.w;
        }
    }

    const int rg = tid >> 4, cg = tid & 15;
    const int r0 = rg * 4, c0 = cg * 12;
    float acc[4][12] = {};

    for (int kk = 0; kk < 192; kk += 32) {
        __syncthreads();
#pragma unroll
        for (int i = 0; i < 6; ++i) {
            int f = tid + 256 * i;          // 0..1535
            int k2 = f / 48, c4 = f % 48;
            *(float4*)&Bs[k2 * 192 + c4 * 4] = *(const float4*)&W[(size_t)(kk + k2) * 192 + c4 * 4];
        }
        __syncthreads();
#pragma unroll
        for (int k2 = 0; k2 < 32; ++k2) {
            const float4 a  = *(const float4*)&As[(kk + k2) * 64 + r0];
            const float4 b0 = *(const float4*)&Bs[k2 * 192 + c0];
            const float4 b1 = *(const float4*)&Bs[k2 * 192 + c0 + 4];
            const float4 b2 = *(const float4*)&Bs[k2 * 192 + c0 + 8];
            const float ar[4] = {a.x, a.y, a.z, a.w};
#pragma unroll
            for (int r = 0; r < 4; ++r) {
                acc[r][0] = fmaf(ar[r], b0.x, acc[r][0]);
                acc[r][1] = fmaf(ar[r], b0.y, acc[r][1]);
                acc[r][2] = fmaf(ar[r], b0.z, acc[r][2]);
                acc[r][3] = fmaf(ar[r], b0.w, acc[r][3]);
                acc[r][4] = fmaf(ar[r], b1.x, acc[r][4]);
                acc[r][5] = fmaf(ar[r], b1.y, acc[r][5]);
                acc[r][6] = fmaf(ar[r], b1.z, acc[r][6]);
                acc[r][7] = fmaf(ar[r], b1.w, acc[r][7]);
                acc[r][8] = fmaf(ar[r], b2.x, acc[r][8]);
                acc[r][9] = fmaf(ar[r], b2.y, acc[r][9]);
                acc[r][10] = fmaf(ar[r], b2.z, acc[r][10]);
                acc[r][11] = fmaf(ar[r], b2.w, acc[r][11]);
            }
        }
    }

    const int h = cg >> 1, d24 = (cg & 1) * 12;
    const float4 bj0 = *(const float4*)&bb[c0];
    const float4 bj1 = *(const float4*)&bb[c0 + 4];
    const float4 bj2 = *(const float4*)&bb[c0 + 8];
#pragma unroll
    for (int r = 0; r < 4; ++r) {
        int row = row0 + r0 + r;
        int b = row >> 9, l = row & 511;
        float* o = op + ((((size_t)b * 3 + g) * HDIM + h) * LDIM + l) * DK3 + d24;
        *(float4*)(o + 0) = make_float4(acc[r][0] + bj0.x, acc[r][1] + bj0.y,
                                        acc[r][2] + bj0.z, acc[r][3] + bj0.w);
        *(float4*)(o + 4) = make_float4(acc[r][4] + bj1.x, acc[r][5] + bj1.y,
                                        acc[r][6] + bj1.z, acc[r][7] + bj1.w);
        *(float4*)(o + 8) = make_float4(acc[r][8] + bj2.x, acc[r][9] + bj2.y,
                                        acc[r][10] + bj2.z, acc[r][11] + bj2.w);
    }
}

// ---------------------------------------------------------------------------
// K2: pairBias.  ONE THREAD = ONE (b,i,j) ROW.  LN folded analytically.
// grid=2048 (no swizzle -- R14's remap regressed badly).
// ---------------------------------------------------------------------------
__global__ __launch_bounds__(256) void k_pairbias(
    const float* __restrict__ pairX, const float* __restrict__ wph,
    const float* __restrict__ csum, float* __restrict__ bias)
{
    const int row = blockIdx.x * 256 + threadIdx.x;
    const float* rp = pairX + (size_t)row * CPD;

    float acc[8] = {};
    float sum = 0.f, sumsq = 0.f;
    for (int s = 0; s < 8; ++s) {
        float rr[16];
        *(float4*)&rr[0]  = *(const float4*)(rp + s * 16 + 0);
        *(float4*)&rr[4]  = *(const float4*)(rp + s * 16 + 4);
        *(float4*)&rr[8]  = *(const float4*)(rp + s * 16 + 8);
        *(float4*)&rr[12] = *(const float4*)(rp + s * 16 + 12);
#pragma unroll
        for (int k = 0; k < 16; ++k) { sum += rr[k]; sumsq = fmaf(rr[k], rr[k], sumsq); }
        const float* wp_s = wph + s * 16;
#pragma unroll
        for (int h = 0; h < 8; ++h) {
            const float* w = wp_s + h * 128;   // uniform address -> s_load
#pragma unroll
            for (int k = 0; k < 16; ++k) acc[h] = fmaf(rr[k], w[k], acc[h]);
        }
    }
    const float m = sum * (1.f / 128.f);
    const float inv = rsqrtf(sumsq * (1.f / 128.f) - m * m + 1e-6f);
    const int b = row >> 18;
    const int ij = row & 262143;
    float* bo = bias + ((size_t)b << 21) + ij;
#pragma unroll
    for (int h = 0; h < 8; ++h) {
        float o = inv * (acc[h] - m * csum[h]) + csum[8 + h];
        bo[(size_t)h << 18] = o;
    }
}

// ---------------------------------------------------------------------------
// K3: oriQK = q.k^T (K=24) + bias.  grid=768.
// ---------------------------------------------------------------------------
__global__ __launch_bounds__(256) void k_qkmat(
    const float* __restrict__ q, const float* __restrict__ k,
    const float* __restrict__ bias, float* __restrict__ oriQK)
{
    __shared__ float Kl[512 * 28];   // 57.3 KB
    __shared__ float Ql[32 * 28];
    const int tid = threadIdx.x;
    const int bch = blockIdx.x >> 4;       // b*24 + c*8 + h
    const int itile = blockIdx.x & 15;
    const float* kp = k + (size_t)bch * 512 * 24;
    const float* qp = q + (size_t)bch * 512 * 24 + (size_t)itile * 32 * 24;
    for (int idx = tid; idx < 512 * 24; idx += 256) {
        int j = idx / 24, d = idx - j * 24;
        Kl[j * 28 + d] = kp[idx];
    }
    for (int idx = tid; idx < 32 * 24; idx += 256) {
        int i = idx / 24, d = idx - i * 24;
        Ql[i * 28 + d] = qp[idx];
    }
    __syncthreads();

    const int ti = tid >> 4, tj = tid & 15;
    const int b = bch / 24, h = bch & 7;
    const float* biasp = bias + ((size_t)(b * 8 + h) * 512 + itile * 32) * 512;
    float* outp = oriQK + (size_t)bch * 262144 + (size_t)itile * 32 * 512;

    for (int cc = 0; cc < 4; ++cc) {
        float acc[2][8] = {};
#pragma unroll
        for (int d4 = 0; d4 < 6; ++d4) {
            const float4 q0 = *(const float4*)&Ql[(ti * 2 + 0) * 28 + d4 * 4];
            const float4 q1 = *(const float4*)&Ql[(ti * 2 + 1) * 28 + d4 * 4];
#pragma unroll
            for (int u = 0; u < 8; ++u) {
                const float4 kv = *(const float4*)&Kl[(cc * 128 + u * 16 + tj) * 28 + d4 * 4];
                acc[0][u] = fmaf(q0.x, kv.x, fmaf(q0.y, kv.y, fmaf(q0.z, kv.z, fmaf(q0.w, kv.w, acc[0][u]))));
                acc[1][u] = fmaf(q1.x, kv.x, fmaf(q1.y, kv.y, fmaf(q1.z, kv.z, fmaf(q1.w, kv.w, acc[1][u]))));
            }
        }
#pragma unroll
        for (int r = 0; r < 2; ++r) {
            int i = ti * 2 + r;
#pragma unroll
            for (int u = 0; u < 8; ++u) {
                int j = cc * 128 + u * 16 + tj;
                outp[(size_t)i * 512 + j] = acc[r][u] + biasp[(size_t)i * 512 + j];
            }
        }
    }
}

// ---------------------------------------------------------------------------
// K4 v11: conv v9 + UNROLLED c-loop with cen[3][8][2] register capture
// (all indices compile-time -> register file, no scratch; this removes the
// 50 MB epilogue center re-read from global that v9 paid).
// 32x16 tiles, grid=1024, LDS 34 KB.
// ---------------------------------------------------------------------------
__global__ __launch_bounds__(256, 4) void k_conv(
    const float* __restrict__ oriQK, const float* __restrict__ convW, const float* __restrict__ convB,
    const float* __restrict__ Wpr, const float* __restrict__ bpr,
    float* __restrict__ qk, float* __restrict__ out2)
{
    __shared__ float tile[8 * 36 * 24];   // 27648 B: conv tile, later gql overlay
    __shared__ float wT[1600];            // 6400 B
    const int tid = threadIdx.x;
    const int bx = blockIdx.x;
    const int b = bx >> 9, rem = bx & 511;
    const int i0 = (rem >> 5) * 32, j0 = (rem & 31) * 16;

    const int jg = tid & 7, ii = tid >> 3;
    const int j2 = jg * 2;
    float acc[8][2] = {};                    // conv partial sums
    float cen[3][8][2];                      // branch centers (static idx, regs)

#pragma unroll
    for (int c = 0; c < 3; ++c) {
        __syncthreads();
        for (int i = tid; i < 1600; i += 256) {
            int h = i & 7, rest = i >> 3;
            int tap = rest % 25, hi = rest / 25;
            wT[hi * 200 + tap * 8 + h] = convW[c * 1600 + h * 200 + hi * 25 + tap];
        }
        for (int idx = tid; idx < 8 * 720; idx += 256) {
            int ch = idx / 720;
            int r = idx - ch * 720;
            int iw = r / 20, jw = r - iw * 20;
            int gi = i0 - 2 + iw, gj = j0 - 2 + jw;
            float v = 0.f;
            if ((unsigned)gi < 512u && (unsigned)gj < 512u)
                v = oriQK[((size_t)(b * 24 + c * 8 + ch) << 18) + ((size_t)gi << 9) + gj];
            tile[ch * 864 + iw * 24 + jw] = v;
        }
        __syncthreads();

        for (int hi = 0; hi < 8; ++hi) {
            const float* tch = &tile[hi * 864];
            const float* wch = &wT[hi * 200];
#pragma unroll
            for (int kh = 0; kh < 5; ++kh) {
                const float* trow = &tch[(ii + kh) * 24 + j2];
                float v[6];
                *(float2*)&v[0] = *(const float2*)&trow[0];
                *(float2*)&v[2] = *(const float2*)&trow[2];
                *(float2*)&v[4] = *(const float2*)&trow[4];
#pragma unroll
                for (int kw = 0; kw < 5; ++kw) {
                    const float4 wA = *(const float4*)&wch[(kh * 5 + kw) * 8];     // broadcast
                    const float4 wB = *(const float4*)&wch[(kh * 5 + kw) * 8 + 4]; // broadcast
#pragma unroll
                    for (int j = 0; j < 2; ++j) {
                        float vv = v[kw + j];
                        acc[0][j] = fmaf(wA.x, vv, acc[0][j]);
                        acc[1][j] = fmaf(wA.y, vv, acc[1][j]);
                        acc[2][j] = fmaf(wA.z, vv, acc[2][j]);
                        acc[3][j] = fmaf(wA.w, vv, acc[3][j]);
                        acc[4][j] = fmaf(wB.x, vv, acc[4][j]);
                        acc[5][j] = fmaf(wB.y, vv, acc[5][j]);
                        acc[6][j] = fmaf(wB.z, vv, acc[6][j]);
                        acc[7][j] = fmaf(wB.w, vv, acc[7][j]);
                    }
                }
            }
        }
        // capture this branch's centers while the tile is live (static c)
#pragma unroll
        for (int h = 0; h < 8; ++h) {
            const float* tr = &tile[h * 864 + (ii + 2) * 24 + j2 + 2];
            cen[c][h][0] = tr[0];
            cen[c][h][1] = tr[1];
        }
    }

    // epilogue 1: qk writes from registers + gelu(mean)
    const int gi = i0 + ii, gj = j0 + j2;
    float* qkb = qk + ((size_t)(b * 24) << 18) + ((size_t)gi << 9) + gj;
#pragma unroll
    for (int h = 0; h < 8; ++h) {
        float cv = convB[h] + convB[8 + h] + convB[16 + h];   // uniform
        float cj0 = acc[h][0] + cv, cj1 = acc[h][1] + cv;
        float mm0 = cen[0][h][0] + cen[1][h][0] + cen[2][h][0];
        float mm1 = cen[0][h][1] + cen[1][h][1] + cen[2][h][1];
#pragma unroll
        for (int c = 0; c < 3; ++c) {
            float2 o = make_float2((cen[c][h][0] + cj0) * INV_DIV,
                                   (cen[c][h][1] + cj1) * INV_DIV);
            *(float2*)(qkb + ((size_t)(c * 8 + h) << 18)) = o;
        }
        acc[h][0] = gelu_exact((mm0 * (1.f / 3.f) + cj0) * INV_DIV);
        acc[h][1] = gelu_exact((mm1 * (1.f / 3.f) + cj1) * INV_DIV);
    }
    __syncthreads();   // all tile reads done; smem becomes gql

    // gql overlay [h][512]
    float* gql = tile;
#pragma unroll
    for (int h = 0; h < 8; ++h)
        *(float2*)&gql[h * 512 + ii * 16 + j2] = make_float2(acc[h][0], acc[h][1]);
    __syncthreads();

    // epilogue 2: out2[pos][0..127] = gq[pos] . Wpr + bpr (nontemporal)
    const int pq = tid & 31, pg = tid >> 5;   // pg 0..7
    float4 wv[8];
#pragma unroll
    for (int h = 0; h < 8; ++h) wv[h] = *(const float4*)&Wpr[h * 128 + pq * 4];
    const float4 bv = *(const float4*)&bpr[pq * 4];

    for (int it = 0; it < 64; ++it) {
        int pos = it * 8 + pg;
        float g8[8];
#pragma unroll
        for (int h = 0; h < 8; ++h) g8[h] = gql[h * 512 + pos];   // broadcast
        float ox = bv.x + g8[0]*wv[0].x + g8[1]*wv[1].x + g8[2]*wv[2].x + g8[3]*wv[3].x
                 + g8[4]*wv[4].x + g8[5]*wv[5].x + g8[6]*wv[6].x + g8[7]*wv[7].x;
        float oy = bv.y + g8[0]*wv[0].y + g8[1]*wv[1].y + g8[2]*wv[2].y + g8[3]*wv[3].y
                 + g8[4]*wv[4].y + g8[5]*wv[5].y + g8[6]*wv[6].y + g8[7]*wv[7].y;
        float oz = bv.z + g8[0]*wv[0].z + g8[1]*wv[1].z + g8[2]*wv[2].z + g8[3]*wv[3].z
                 + g8[4]*wv[4].z + g8[5]*wv[5].z + g8[6]*wv[6].z + g8[7]*wv[7].z;
        float ow = bv.w + g8[0]*wv[0].w + g8[1]*wv[1].w + g8[2]*wv[2].w + g8[3]*wv[3].w
                 + g8[4]*wv[4].w + g8[5]*wv[5].w + g8[6]*wv[6].w + g8[7]*wv[7].w;
        int oi = i0 + (pos >> 4), oj = j0 + (pos & 15);
        nt_store4(&out2[(((size_t)(b * 512 + oi) << 9) + oj) * 128 + pq * 4], ox, oy, oz, ow);
    }
}

// ---------------------------------------------------------------------------
// K6: softmax + P@V + sigmoid(gate).  Reads materialized qk.  Vl stride 28
// (16B-aligned, conflict-benign).  Two-stage reduce.  grid=768.
// ---------------------------------------------------------------------------
__global__ __launch_bounds__(256) void k_softmax_pv(
    const float* __restrict__ qk, const float* __restrict__ v, const float* __restrict__ gate,
    float* __restrict__ houts)
{
    __shared__ float Vl[512 * 28];   // 57.3 KB
    const int tid = threadIdx.x;
    const int bch = blockIdx.x >> 4, itile = blockIdx.x & 15;
    const float* vp = v + (size_t)bch * (512 * 24);
    for (int idx = tid; idx < 512 * 24; idx += 256) {
        int j = idx / 24, d = idx - j * 24;
        Vl[j * 28 + d] = vp[idx];
    }
    __syncthreads();

    const int wid = tid >> 6, lane = tid & 63;
    const int b = bch / 24, c = (bch % 24) >> 3, h = bch & 7;
    const int tg = lane >> 3;          // d-trio group 0..7
    for (int rr = 0; rr < 8; ++rr) {
        const int i = itile * 32 + wid * 8 + rr;
        const float* row = qk + ((size_t)bch * 512 + i) * 512;
        float e[8]; float mx = -1e30f;
#pragma unroll
        for (int u = 0; u < 8; ++u) { e[u] = row[lane + 64 * u]; mx = fmaxf(mx, e[u]); }
#pragma unroll
        for (int o = 32; o; o >>= 1) mx = fmaxf(mx, __shfl_xor(mx, o));
        float s = 0.f;
#pragma unroll
        for (int u = 0; u < 8; ++u) { e[u] = __expf(e[u] - mx); s += e[u]; }
#pragma unroll
        for (int o = 32; o; o >>= 1) s += __shfl_xor(s, o);
        float inv = 1.f / s;

        float4 a4[6] = {};
#pragma unroll
        for (int u = 0; u < 8; ++u) {
            float p = e[u] * inv;
            const float* vr = &Vl[(u * 64 + lane) * 28];
#pragma unroll
            for (int k = 0; k < 6; ++k) {
                float4 vv = *(const float4*)(vr + 4 * k);
                a4[k].x = fmaf(p, vv.x, a4[k].x);
                a4[k].y = fmaf(p, vv.y, a4[k].y);
                a4[k].z = fmaf(p, vv.z, a4[k].z);
                a4[k].w = fmaf(p, vv.w, a4[k].w);
            }
        }
        // stage 1: reduce over lane bits 3,4,5 -> class (lane&7) partials
#pragma unroll
        for (int k = 0; k < 6; ++k) {
            a4[k].x += __shfl_xor(a4[k].x, 8);  a4[k].y += __shfl_xor(a4[k].y, 8);
            a4[k].z += __shfl_xor(a4[k].z, 8);  a4[k].w += __shfl_xor(a4[k].w, 8);
            a4[k].x += __shfl_xor(a4[k].x, 16); a4[k].y += __shfl_xor(a4[k].y, 16);
            a4[k].z += __shfl_xor(a4[k].z, 16); a4[k].w += __shfl_xor(a4[k].w, 16);
            a4[k].x += __shfl_xor(a4[k].x, 32); a4[k].y += __shfl_xor(a4[k].y, 32);
            a4[k].z += __shfl_xor(a4[k].z, 32); a4[k].w += __shfl_xor(a4[k].w, 32);
        }
        // stage 2: lane selects d-trio tg, reduce across classes (bits 0..2)
        const float af[24] = {
            a4[0].x, a4[0].y, a4[0].z, a4[0].w, a4[1].x, a4[1].y, a4[1].z, a4[1].w,
            a4[2].x, a4[2].y, a4[2].z, a4[2].w, a4[3].x, a4[3].y, a4[3].z, a4[3].w,
            a4[4].x, a4[4].y, a4[4].z, a4[4].w, a4[5].x, a4[5].y, a4[5].z, a4[5].w };
        float w0 = tg==0?af[0]:tg==1?af[3]:tg==2?af[6]:tg==3?af[9]:tg==4?af[12]:tg==5?af[15]:tg==6?af[18]:af[21];
        float w1 = tg==0?af[1]:tg==1?af[4]:tg==2?af[7]:tg==3?af[10]:tg==4?af[13]:tg==5?af[16]:tg==6?af[19]:af[22];
        float w2 = tg==0?af[2]:tg==1?af[5]:tg==2?af[8]:tg==3?af[11]:tg==4?af[14]:tg==5?af[17]:tg==6?af[20]:af[23];
#pragma unroll
        for (int o = 1; o < 8; o <<= 1) {
            w0 += __shfl_xor(w0, o);
            w1 += __shfl_xor(w1, o);
            w2 += __shfl_xor(w2, o);
        }
        if ((lane & 7) == 0) {
            const int d0 = tg * 3;
            const float* gp = gate + ((size_t)bch * 512 + i) * 24 + d0;
            float* op = houts + ((size_t)(b * 512 + i)) * 576 + c * 192 + h * 24 + d0;
            op[0] = w0 / (1.f + __expf(-gp[0]));
            op[1] = w1 / (1.f + __expf(-gp[1]));
            op[2] = w2 / (1.f + __expf(-gp[2]));
        }
    }
}

// ---------------------------------------------------------------------------
// K7: out1 = houts @ Wo + bo + x*g.  Tiled GEMM: 32x64 tile, BK=32, grid=288.
// ---------------------------------------------------------------------------
__global__ __launch_bounds__(256) void k_out1(
    const float* __restrict__ houts, const float* __restrict__ Wo, const float* __restrict__ bo,
    const float* __restrict__ x, const float* __restrict__ gsc,
    float* __restrict__ out1)
{
    __shared__ float As[32 * 33];
    __shared__ float Bs[32 * 64];
    const int tid = threadIdx.x;
    const int mt = blockIdx.x / 9, nt = blockIdx.x % 9;
    const int m0 = mt * 32, n0 = nt * 64;
    const int tn = tid & 15, tm = tid >> 4;
    float acc[2][4] = {};

    for (int kk = 0; kk < 576; kk += 32) {
        {
            int idx = tid;
#pragma unroll
            for (int i = 0; i < 4; ++i, idx += 256) {
                int k2 = idx & 31, m = idx >> 5;
                As[m * 33 + k2] = houts[(size_t)(m0 + m) * 576 + kk + k2];
            }
        }
        {
            int idx = tid;
#pragma unroll
            for (int i = 0; i < 8; ++i, idx += 256) {
                int n = idx & 63, k2 = idx >> 6;
                Bs[k2 * 64 + n] = Wo[(size_t)(kk + k2) * 576 + n0 + n];
            }
        }
        __syncthreads();
#pragma unroll
        for (int k2 = 0; k2 < 32; ++k2) {
            float a0 = As[(tm * 2 + 0) * 33 + k2];
            float a1 = As[(tm * 2 + 1) * 33 + k2];
            const float4 bv = *(const float4*)&Bs[k2 * 64 + tn * 4];
            acc[0][0] += a0 * bv.x; acc[0][1] += a0 * bv.y; acc[0][2] += a0 * bv.z; acc[0][3] += a0 * bv.w;
            acc[1][0] += a1 * bv.x; acc[1][1] += a1 * bv.y; acc[1][2] += a1 * bv.z; acc[1][3] += a1 * bv.w;
        }
        __syncthreads();
    }

    const float gv = gsc[0];
    const float4 b4 = *(const float4*)&bo[n0 + tn * 4];
#pragma unroll
    for (int r = 0; r < 2; ++r) {
        size_t row = (size_t)m0 + tm * 2 + r;
        size_t off = row * 576 + n0 + tn * 4;
        const float4 x4 = *(const float4*)&x[off];
        nt_store4(&out1[off],
                  acc[r][0] + b4.x + x4.x * gv,
                  acc[r][1] + b4.y + x4.y * gv,
                  acc[r][2] + b4.z + x4.z * gv,
                  acc[r][3] + b4.w + x4.w * gv);
    }
}

// ---------------------------------------------------------------------------
extern "C" void kernel_launch(void* const* d_in, const int* in_sizes, int n_in,
                              void* d_out, int out_size, void* d_ws, size_t ws_size,
                              hipStream_t stream) {
    const float* x     = (const float*)d_in[0];
    const float* pairX = (const float*)d_in[1];
    const float* g     = (const float*)d_in[2];
    const float* ln1w  = (const float*)d_in[3];
    const float* ln1b  = (const float*)d_in[4];
    const float* ln2w  = (const float*)d_in[5];
    const float* ln2b  = (const float*)d_in[6];
    const float* Wq    = (const float*)d_in[7];
    const float* bq    = (const float*)d_in[8];
    const float* Wk    = (const float*)d_in[9];
    const float* bk    = (const float*)d_in[10];
    const float* Wv    = (const float*)d_in[11];
    const float* bv    = (const float*)d_in[12];
    const float* Wg    = (const float*)d_in[13];
    const float* bg    = (const float*)d_in[14];
    const float* convW = (const float*)d_in[15];
    const float* convB = (const float*)d_in[16];
    const float* Wp    = (const float*)d_in[17];
    const float* bp    = (const float*)d_in[18];
    const float* Wpr   = (const float*)d_in[19];
    const float* bpr   = (const float*)d_in[20];
    const float* Wo    = (const float*)d_in[21];
    const float* bo    = (const float*)d_in[22];

    float* ws   = (float*)d_ws;
    float* q    = ws + OFF_Q;
    float* k    = ws + OFF_K;
    float* vv   = ws + OFF_V;
    float* gt   = ws + OFF_G;
    float* bias = ws + OFF_BIAS;
    float* ori  = ws + OFF_ORI;
    float* qkb  = ws + OFF_QK;
    float* xn   = ws + OFF_XN;     // alias onto qk region (dead until k_conv)
    float* hout = ws + OFF_H;
    float* wph  = ws + OFF_WPH;
    float* csum = ws + OFF_CS;

    float* out1 = (float*)d_out;
    float* out2 = out1 + 589824;

    k_prep<<<dim3(1), dim3(256), 0, stream>>>(ln2w, ln2b, Wp, bp, wph, csum);
    k_ln<<<dim3(256), dim3(256), 0, stream>>>(x, ln1w, ln1b, xn);
    k_proj<<<dim3(192), dim3(256), 0, stream>>>(xn, Wq, bq, Wk, bk, Wv, bv, Wg, bg,
                                                q, k, vv, gt);
    k_pairbias<<<dim3(2048), dim3(256), 0, stream>>>(pairX, wph, csum, bias);
    k_qkmat<<<dim3(768), dim3(256), 0, stream>>>(q, k, bias, ori);
    k_conv<<<dim3(1024), dim3(256), 0, stream>>>(ori, convW, convB, Wpr, bpr, qkb, out2);
    k_softmax_pv<<<dim3(768), dim3(256), 0, stream>>>(qkb, vv, gt, hout);
    k_out1<<<dim3(288), dim3(256), 0, stream>>>(hout, Wo, bo, x, g, out1);
}